// Round 7
// baseline (279.020 us; speedup 1.0000x reference)
//
#include <hip/hip_runtime.h>

#define BATCH 131072
#define SN 32
#define H1 10
#define H2 6
#define ROWS 128                           // rows per block; lane pairs (lane, lane+64)
#define GRID (BATCH / ROWS)                // 1024
#define LDS_STRIDE 33                      // bank = (row + s) % 32 -> 2-way (free)

typedef float v2f __attribute__((ext_vector_type(2)));

__device__ __forceinline__ v2f bc(float s) { v2f r; r.x = s; r.y = s; return r; }
__device__ __forceinline__ v2f fma2(v2f a, v2f b, v2f c) {
    return __builtin_elementwise_fma(a, b, c);   // -> v_pk_fma_f32
}
__device__ __forceinline__ v2f tanh2(v2f x) {
    // tanh(x) = 1 - 2/(exp(2x)+1); exp/rcp scalar per component, rest packed
    v2f x2 = x + x;
    v2f e; e.x = __expf(x2.x); e.y = __expf(x2.y);
    v2f e1 = e + bc(1.0f);
    v2f r; r.x = __builtin_amdgcn_rcpf(e1.x); r.y = __builtin_amdgcn_rcpf(e1.y);
    return fma2(bc(-2.0f), r, bc(1.0f));
}

// 1024 blocks x 256 threads; block: 128 rows x 32 subnets; wave handles 8
// subnets sequentially, each lane computes a ROW PAIR via packed fp32.
// Column s of xt is read for the LAST time by wave (s%4) at iter (s>>2), so
// raw outputs overwrite xt in place -> 16.9 KB LDS -> 8 blocks/CU ceiling.
__global__ __launch_bounds__(256, 8) void k_main(
    const float* __restrict__ x,
    const float* __restrict__ W1, const float* __restrict__ B1,
    const float* __restrict__ W2, const float* __restrict__ B2,
    const float* __restrict__ W3, const float* __restrict__ B3,
    float* __restrict__ out, float* __restrict__ partial /* [3*SN][GRID] */)
{
    __shared__ float xt[ROWS * LDS_STRIDE];   // 16.9 KB (x tile, then raw outputs)
    const int tid = threadIdx.x;
    const int lane = tid & 63;
    const int wave = tid >> 6;                // 0..3
    const int blk = blockIdx.x;

    // stage 128x32 x-tile coalesced, transpose-pad into LDS (4 float4/thread)
    const float4* xv = (const float4*)(x + (size_t)blk * ROWS * SN);
    #pragma unroll
    for (int it = 0; it < 4; ++it) {
        int v = it * 256 + tid;
        float4 val = xv[v];
        int r = v >> 3;                       // 8 float4 per row
        int c = (v & 7) << 2;
        float* dst = &xt[r * LDS_STRIDE + c];
        dst[0] = val.x; dst[1] = val.y; dst[2] = val.z; dst[3] = val.w;
    }
    __syncthreads();

    #pragma unroll 1
    for (int si = 0; si < 8; ++si) {
        // wave-uniform subnet id -> params land in SGPRs via s_load
        const int s = __builtin_amdgcn_readfirstlane(si * 4 + wave);
        const float* w1p = W1 + s * H1;
        const float* b1p = B1 + s * H1;
        const float* w2p = W2 + s * H1 * H2;
        const float* b2p = B2 + s * H2;
        const float* w3p = W3 + s * H2;
        const float b3 = B3[s];

        float w1r[H1], b1r[H1];
        #pragma unroll
        for (int i = 0; i < H1; ++i) { w1r[i] = w1p[i]; b1r[i] = b1p[i]; }
        float w2r[H1 * H2];
        #pragma unroll
        for (int k = 0; k < H1 * H2; ++k) w2r[k] = w2p[k];
        float b2r[H2], w3r[H2];
        #pragma unroll
        for (int j = 0; j < H2; ++j) { b2r[j] = b2p[j]; w3r[j] = w3p[j]; }

        v2f xs;
        xs.x = xt[lane * LDS_STRIDE + s];
        xs.y = xt[(lane + 64) * LDS_STRIDE + s];

        // layer 1: t = tanh(x w1 + b1); p = (1-t^2) w1; q' = t (1-t^2) w1^2
        // (true d2 = -2 q'; the -2 is reassociated into the g2 epilogue)
        v2f t[H1], p[H1], q[H1];
        #pragma unroll
        for (int i = 0; i < H1; ++i) {
            v2f u = fma2(xs, bc(w1r[i]), bc(b1r[i]));
            v2f ti = tanh2(u);
            v2f e = fma2(-ti, ti, bc(1.0f));
            t[i] = ti;
            p[i] = e * bc(w1r[i]);
            q[i] = (ti * p[i]) * bc(w1r[i]);
        }

        v2f o = bc(b3), g2a = bc(0.0f);
        #pragma unroll
        for (int j = 0; j < H2; ++j) {
            v2f vv = bc(b2r[j]), a = bc(0.0f), c = bc(0.0f);
            #pragma unroll
            for (int i = 0; i < H1; ++i) {
                v2f wb = bc(w2r[i * H2 + j]);
                vv = fma2(wb, t[i], vv);
                a  = fma2(wb, p[i], a);
                c  = fma2(wb, q[i], c);
            }
            v2f sj = tanh2(vv);
            v2f dj = fma2(-sj, sj, bc(1.0f));            // 1 - s^2
            v2f aa = a * a;
            v2f h  = fma2(sj, aa, c);                    // c' + s a^2
            v2f k  = dj * h;                             // g2_j = -2 k
            o   = fma2(bc(w3r[j]), sj, o);
            g2a = fma2(bc(w3r[j]), k, g2a);              // g2_true = -2 g2a
        }

        // raw outputs overwrite the just-consumed xt column (same wave, same iter)
        xt[lane * LDS_STRIDE + s] = o.x;
        xt[(lane + 64) * LDS_STRIDE + s] = o.y;

        // per-pair partial sums, horizontal add, wave butterfly reduce
        v2f s2v = o * o;
        v2f s3v = (g2a * g2a) * bc(4.0f);                // (-2 g2a)^2
        float s1 = o.x + o.y;
        float s2 = s2v.x + s2v.y;
        float s3 = s3v.x + s3v.y;
        #pragma unroll
        for (int off = 32; off > 0; off >>= 1) {
            s1 += __shfl_xor(s1, off);
            s2 += __shfl_xor(s2, off);
            s3 += __shfl_xor(s3, off);
        }
        if (lane == 0) {
            partial[(size_t)(0 * SN + s) * GRID + blk] = s1;
            partial[(size_t)(1 * SN + s) * GRID + blk] = s2;
            partial[(size_t)(2 * SN + s) * GRID + blk] = s3;
        }
    }
    __syncthreads();

    // coalesced raw-output store: lane reads 4 floats (banks 4k+r, conflict-free)
    float4* po = (float4*)out;
    const size_t base = (size_t)blk * (ROWS * SN / 4);
    #pragma unroll
    for (int it = 0; it < 4; ++it) {
        int v = it * 256 + tid;
        int r = v >> 3;
        int c = (v & 7) << 2;
        const float* src = &xt[r * LDS_STRIDE + c];
        float4 w; w.x = src[0]; w.y = src[1]; w.z = src[2]; w.w = src[3];
        po[base + v] = w;
    }
}

// 96 blocks: block b sums partial[b][0..GRID) (coalesced) -> acc[b] (double)
__global__ __launch_bounds__(256) void k_reduce(const float* __restrict__ partial,
                                                double* __restrict__ acc)
{
    const float* p = partial + (size_t)blockIdx.x * GRID;
    double s = 0.0;
    for (int i = threadIdx.x; i < GRID; i += 256) s += (double)p[i];
    #pragma unroll
    for (int off = 32; off > 0; off >>= 1) s += __shfl_down(s, off);
    __shared__ double ws[4];
    if ((threadIdx.x & 63) == 0) ws[threadIdx.x >> 6] = s;
    __syncthreads();
    if (threadIdx.x == 0) acc[blockIdx.x] = ws[0] + ws[1] + ws[2] + ws[3];
}

// stats recomputed per block from acc (96 doubles, cheap); block 0 writes loss
__global__ __launch_bounds__(256) void k_norm(float* __restrict__ out,
                                              const double* __restrict__ acc)
{
    __shared__ float mean_s[SN], inv_s[SN];
    const int tid = threadIdx.x;
    if (tid < SN) {
        const double invB = 1.0 / (double)BATCH;
        double mean = acc[tid] * invB;
        double var = acc[SN + tid] * invB - mean * mean;
        if (var < 0.0) var = 0.0;
        mean_s[tid] = (float)mean;
        inv_s[tid] = (float)(1.0 / sqrt(var + 1e-10));
    }
    if (blockIdx.x == 0 && tid == 0) {
        const double invB = 1.0 / (double)BATCH;
        double sum = 0.0;
        for (int s = 0; s < SN; ++s) {
            double mean = acc[s] * invB;
            double var = acc[SN + s] * invB - mean * mean;
            if (var < 0.0) var = 0.0;
            sum += (acc[2 * SN + s] * invB) / sqrt(var);   // no eps (matches ref)
        }
        out[(size_t)BATCH * SN] = (float)(0.001 * sum);
    }
    __syncthreads();
    const int v = blockIdx.x * 256 + tid;                  // float4 index
    float4* p = (float4*)out;
    float4 val = p[v];
    const int c = (v & 7) << 2;                            // subnet base
    val.x = (val.x - mean_s[c + 0]) * inv_s[c + 0];
    val.y = (val.y - mean_s[c + 1]) * inv_s[c + 1];
    val.z = (val.z - mean_s[c + 2]) * inv_s[c + 2];
    val.w = (val.w - mean_s[c + 3]) * inv_s[c + 3];
    p[v] = val;
}

extern "C" void kernel_launch(void* const* d_in, const int* in_sizes, int n_in,
                              void* d_out, int out_size, void* d_ws, size_t ws_size,
                              hipStream_t stream) {
    const float* x  = (const float*)d_in[0];
    const float* W1 = (const float*)d_in[1];
    const float* B1 = (const float*)d_in[2];
    const float* W2 = (const float*)d_in[3];
    const float* B2 = (const float*)d_in[4];
    const float* W3 = (const float*)d_in[5];
    const float* B3 = (const float*)d_in[6];

    float* out = (float*)d_out;                 // [BATCH*SN] out_bn, then [1] loss
    float* partial = (float*)d_ws;              // [3*SN][GRID] f32, fully overwritten
    double* acc = (double*)((char*)d_ws + (size_t)3 * SN * GRID * sizeof(float));

    k_main<<<GRID, 256, 0, stream>>>(x, W1, B1, W2, B2, W3, B3, out, partial);
    k_reduce<<<3 * SN, 256, 0, stream>>>(partial, acc);
    k_norm<<<(BATCH * SN / 4) / 256, 256, 0, stream>>>(out, acc);
}

// Round 8
// 124.558 us; speedup vs baseline: 2.2401x; 2.2401x over previous
//
#include <hip/hip_runtime.h>

#define BATCH 131072
#define SN 32
#define H1 10
#define H2 6
#define ROWS 128                           // rows per block; lane pairs (lane, lane+64)
#define GRID (BATCH / ROWS)                // 1024
#define LDS_STRIDE 33                      // bank = (row + s) % 32 -> 2-way (free)

typedef float v2f __attribute__((ext_vector_type(2)));

__device__ __forceinline__ v2f bc(float s) { v2f r; r.x = s; r.y = s; return r; }
__device__ __forceinline__ v2f fma2(v2f a, v2f b, v2f c) {
    return __builtin_elementwise_fma(a, b, c);   // -> v_pk_fma_f32
}
__device__ __forceinline__ v2f tanh2(v2f x) {
    // tanh(x) = 1 - 2/(exp(2x)+1); exp/rcp scalar per component, rest packed
    v2f x2 = x + x;
    v2f e; e.x = __expf(x2.x); e.y = __expf(x2.y);
    v2f e1 = e + bc(1.0f);
    v2f r; r.x = __builtin_amdgcn_rcpf(e1.x); r.y = __builtin_amdgcn_rcpf(e1.y);
    return fma2(bc(-2.0f), r, bc(1.0f));
}

// 1024 blocks x 256 threads; block: 128 rows x 32 subnets; wave handles 8
// subnets sequentially, each lane computes a ROW PAIR via packed fp32.
// Column s of xt is read for the LAST time by wave (s%4) at iter (s>>2), so
// raw outputs overwrite xt in place -> 16.9 KB LDS.
// NOTE: plain launch_bounds(256). R7's (256,8) capped VGPR at 64 and SPILLED
// (FETCH 8->284 MB, WRITE 19->502 MB). VGPR ~52 <= 64 already permits
// 8 waves/SIMD; LDS 16.9 KB * 8 = 135 KB <= 160 KB -> 8 blocks/CU by math.
__global__ __launch_bounds__(256) void k_main(
    const float* __restrict__ x,
    const float* __restrict__ W1, const float* __restrict__ B1,
    const float* __restrict__ W2, const float* __restrict__ B2,
    const float* __restrict__ W3, const float* __restrict__ B3,
    float* __restrict__ out, float* __restrict__ partial /* [3*SN][GRID] */)
{
    __shared__ float xt[ROWS * LDS_STRIDE];   // 16.9 KB (x tile, then raw outputs)
    const int tid = threadIdx.x;
    const int lane = tid & 63;
    const int wave = tid >> 6;                // 0..3
    const int blk = blockIdx.x;

    // stage 128x32 x-tile coalesced, transpose-pad into LDS (4 float4/thread)
    const float4* xv = (const float4*)(x + (size_t)blk * ROWS * SN);
    #pragma unroll
    for (int it = 0; it < 4; ++it) {
        int v = it * 256 + tid;
        float4 val = xv[v];
        int r = v >> 3;                       // 8 float4 per row
        int c = (v & 7) << 2;
        float* dst = &xt[r * LDS_STRIDE + c];
        dst[0] = val.x; dst[1] = val.y; dst[2] = val.z; dst[3] = val.w;
    }
    __syncthreads();

    #pragma unroll 1
    for (int si = 0; si < 8; ++si) {
        // wave-uniform subnet id -> params land in SGPRs via s_load
        const int s = __builtin_amdgcn_readfirstlane(si * 4 + wave);
        const float* w1p = W1 + s * H1;
        const float* b1p = B1 + s * H1;
        const float* w2p = W2 + s * H1 * H2;
        const float* b2p = B2 + s * H2;
        const float* w3p = W3 + s * H2;
        const float b3 = B3[s];

        float w1r[H1], b1r[H1];
        #pragma unroll
        for (int i = 0; i < H1; ++i) { w1r[i] = w1p[i]; b1r[i] = b1p[i]; }
        float w2r[H1 * H2];
        #pragma unroll
        for (int k = 0; k < H1 * H2; ++k) w2r[k] = w2p[k];
        float b2r[H2], w3r[H2];
        #pragma unroll
        for (int j = 0; j < H2; ++j) { b2r[j] = b2p[j]; w3r[j] = w3p[j]; }

        v2f xs;
        xs.x = xt[lane * LDS_STRIDE + s];
        xs.y = xt[(lane + 64) * LDS_STRIDE + s];

        // layer 1: t = tanh(x w1 + b1); p = (1-t^2) w1; q' = t (1-t^2) w1^2
        // (true d2 = -2 q'; the -2 is reassociated into the g2 epilogue)
        v2f t[H1], p[H1], q[H1];
        #pragma unroll
        for (int i = 0; i < H1; ++i) {
            v2f u = fma2(xs, bc(w1r[i]), bc(b1r[i]));
            v2f ti = tanh2(u);
            v2f e = fma2(-ti, ti, bc(1.0f));
            t[i] = ti;
            p[i] = e * bc(w1r[i]);
            q[i] = (ti * p[i]) * bc(w1r[i]);
        }

        v2f o = bc(b3), g2a = bc(0.0f);
        #pragma unroll
        for (int j = 0; j < H2; ++j) {
            v2f vv = bc(b2r[j]), a = bc(0.0f), c = bc(0.0f);
            #pragma unroll
            for (int i = 0; i < H1; ++i) {
                v2f wb = bc(w2r[i * H2 + j]);
                vv = fma2(wb, t[i], vv);
                a  = fma2(wb, p[i], a);
                c  = fma2(wb, q[i], c);
            }
            v2f sj = tanh2(vv);
            v2f dj = fma2(-sj, sj, bc(1.0f));            // 1 - s^2
            v2f aa = a * a;
            v2f h  = fma2(sj, aa, c);                    // c' + s a^2
            v2f k  = dj * h;                             // g2_j = -2 k
            o   = fma2(bc(w3r[j]), sj, o);
            g2a = fma2(bc(w3r[j]), k, g2a);              // g2_true = -2 g2a
        }

        // raw outputs overwrite the just-consumed xt column (same wave, same iter)
        xt[lane * LDS_STRIDE + s] = o.x;
        xt[(lane + 64) * LDS_STRIDE + s] = o.y;

        // per-pair partial sums, horizontal add, wave butterfly reduce
        v2f s2v = o * o;
        v2f s3v = (g2a * g2a) * bc(4.0f);                // (-2 g2a)^2
        float s1 = o.x + o.y;
        float s2 = s2v.x + s2v.y;
        float s3 = s3v.x + s3v.y;
        #pragma unroll
        for (int off = 32; off > 0; off >>= 1) {
            s1 += __shfl_xor(s1, off);
            s2 += __shfl_xor(s2, off);
            s3 += __shfl_xor(s3, off);
        }
        if (lane == 0) {
            partial[(size_t)(0 * SN + s) * GRID + blk] = s1;
            partial[(size_t)(1 * SN + s) * GRID + blk] = s2;
            partial[(size_t)(2 * SN + s) * GRID + blk] = s3;
        }
    }
    __syncthreads();

    // coalesced raw-output store: lane reads 4 floats (banks 4k+r, conflict-free)
    float4* po = (float4*)out;
    const size_t base = (size_t)blk * (ROWS * SN / 4);
    #pragma unroll
    for (int it = 0; it < 4; ++it) {
        int v = it * 256 + tid;
        int r = v >> 3;
        int c = (v & 7) << 2;
        const float* src = &xt[r * LDS_STRIDE + c];
        float4 w; w.x = src[0]; w.y = src[1]; w.z = src[2]; w.w = src[3];
        po[base + v] = w;
    }
}

// 96 blocks: block b sums partial[b][0..GRID) (coalesced) -> acc[b] (double)
__global__ __launch_bounds__(256) void k_reduce(const float* __restrict__ partial,
                                                double* __restrict__ acc)
{
    const float* p = partial + (size_t)blockIdx.x * GRID;
    double s = 0.0;
    for (int i = threadIdx.x; i < GRID; i += 256) s += (double)p[i];
    #pragma unroll
    for (int off = 32; off > 0; off >>= 1) s += __shfl_down(s, off);
    __shared__ double ws[4];
    if ((threadIdx.x & 63) == 0) ws[threadIdx.x >> 6] = s;
    __syncthreads();
    if (threadIdx.x == 0) acc[blockIdx.x] = ws[0] + ws[1] + ws[2] + ws[3];
}

// stats recomputed per block from acc (96 doubles, cheap); block 0 writes loss
__global__ __launch_bounds__(256) void k_norm(float* __restrict__ out,
                                              const double* __restrict__ acc)
{
    __shared__ float mean_s[SN], inv_s[SN];
    const int tid = threadIdx.x;
    if (tid < SN) {
        const double invB = 1.0 / (double)BATCH;
        double mean = acc[tid] * invB;
        double var = acc[SN + tid] * invB - mean * mean;
        if (var < 0.0) var = 0.0;
        mean_s[tid] = (float)mean;
        inv_s[tid] = (float)(1.0 / sqrt(var + 1e-10));
    }
    if (blockIdx.x == 0 && tid == 0) {
        const double invB = 1.0 / (double)BATCH;
        double sum = 0.0;
        for (int s = 0; s < SN; ++s) {
            double mean = acc[s] * invB;
            double var = acc[SN + s] * invB - mean * mean;
            if (var < 0.0) var = 0.0;
            sum += (acc[2 * SN + s] * invB) / sqrt(var);   // no eps (matches ref)
        }
        out[(size_t)BATCH * SN] = (float)(0.001 * sum);
    }
    __syncthreads();
    const int v = blockIdx.x * 256 + tid;                  // float4 index
    float4* p = (float4*)out;
    float4 val = p[v];
    const int c = (v & 7) << 2;                            // subnet base
    val.x = (val.x - mean_s[c + 0]) * inv_s[c + 0];
    val.y = (val.y - mean_s[c + 1]) * inv_s[c + 1];
    val.z = (val.z - mean_s[c + 2]) * inv_s[c + 2];
    val.w = (val.w - mean_s[c + 3]) * inv_s[c + 3];
    p[v] = val;
}

extern "C" void kernel_launch(void* const* d_in, const int* in_sizes, int n_in,
                              void* d_out, int out_size, void* d_ws, size_t ws_size,
                              hipStream_t stream) {
    const float* x  = (const float*)d_in[0];
    const float* W1 = (const float*)d_in[1];
    const float* B1 = (const float*)d_in[2];
    const float* W2 = (const float*)d_in[3];
    const float* B2 = (const float*)d_in[4];
    const float* W3 = (const float*)d_in[5];
    const float* B3 = (const float*)d_in[6];

    float* out = (float*)d_out;                 // [BATCH*SN] out_bn, then [1] loss
    float* partial = (float*)d_ws;              // [3*SN][GRID] f32, fully overwritten
    double* acc = (double*)((char*)d_ws + (size_t)3 * SN * GRID * sizeof(float));

    k_main<<<GRID, 256, 0, stream>>>(x, W1, B1, W2, B2, W3, B3, out, partial);
    k_reduce<<<3 * SN, 256, 0, stream>>>(partial, acc);
    k_norm<<<(BATCH * SN / 4) / 256, 256, 0, stream>>>(out, acc);
}

// Round 9
// 120.761 us; speedup vs baseline: 2.3105x; 1.0314x over previous
//
#include <hip/hip_runtime.h>

#define BATCH 131072
#define SN 32
#define H1 10
#define H2 6
#define ROWS 128                           // rows per block; lane pairs (lane, lane+64)
#define GRID (BATCH / ROWS)                // 1024
#define TPB 512                            // 8 waves/block -> 32 waves/CU at 4 blocks/CU
#define LDS_STRIDE 33                      // bank = (row + s) % 32 -> 2-way (free)

typedef float v2f __attribute__((ext_vector_type(2)));

__device__ __forceinline__ v2f bc(float s) { v2f r; r.x = s; r.y = s; return r; }
__device__ __forceinline__ v2f fma2(v2f a, v2f b, v2f c) {
    return __builtin_elementwise_fma(a, b, c);   // -> v_pk_fma_f32
}
__device__ __forceinline__ v2f tanh2(v2f x) {
    // tanh(x) = 1 - 2/(exp(2x)+1); exp/rcp scalar per component, rest packed
    v2f x2 = x + x;
    v2f e; e.x = __expf(x2.x); e.y = __expf(x2.y);
    v2f e1 = e + bc(1.0f);
    v2f r; r.x = __builtin_amdgcn_rcpf(e1.x); r.y = __builtin_amdgcn_rcpf(e1.y);
    return fma2(bc(-2.0f), r, bc(1.0f));
}

// 1024 blocks x 512 threads (8 waves); block: 128 rows x 32 subnets; wave w
// handles subnets s = si*8+w (si<4), each lane computes a ROW PAIR via packed
// fp32. Column s of xt is last read by its owning wave in the same iteration,
// so raw outputs overwrite xt in place (16.9 KB LDS).
// Resource math: VGPR~48<=64 (8 waves/SIMD), LDS 16.9*4=68KB, 2048 thr/CU
// -> exactly 4 blocks/CU -> 32 waves/CU (100% ceiling; grid was the R8 cap).
// NO min-waves hint: (256,8) in R7 forced VGPR<=64->spill catastrophe.
__global__ __launch_bounds__(TPB) void k_main(
    const float* __restrict__ x,
    const float* __restrict__ W1, const float* __restrict__ B1,
    const float* __restrict__ W2, const float* __restrict__ B2,
    const float* __restrict__ W3, const float* __restrict__ B3,
    float* __restrict__ out, float* __restrict__ partial /* [3*SN][GRID] */)
{
    __shared__ float xt[ROWS * LDS_STRIDE];   // 16.9 KB (x tile, then raw outputs)
    const int tid = threadIdx.x;
    const int lane = tid & 63;
    const int wave = tid >> 6;                // 0..7
    const int blk = blockIdx.x;

    // stage 128x32 x-tile coalesced, transpose-pad into LDS (2 float4/thread)
    const float4* xv = (const float4*)(x + (size_t)blk * ROWS * SN);
    #pragma unroll
    for (int it = 0; it < 2; ++it) {
        int v = it * TPB + tid;
        float4 val = xv[v];
        int r = v >> 3;                       // 8 float4 per row
        int c = (v & 7) << 2;
        float* dst = &xt[r * LDS_STRIDE + c];
        dst[0] = val.x; dst[1] = val.y; dst[2] = val.z; dst[3] = val.w;
    }
    __syncthreads();

    #pragma unroll 1
    for (int si = 0; si < 4; ++si) {
        // wave-uniform subnet id -> params land in SGPRs via s_load
        const int s = __builtin_amdgcn_readfirstlane(si * 8 + wave);
        const float* w1p = W1 + s * H1;
        const float* b1p = B1 + s * H1;
        const float* w2p = W2 + s * H1 * H2;
        const float* b2p = B2 + s * H2;
        const float* w3p = W3 + s * H2;
        const float b3 = B3[s];

        float w1r[H1], b1r[H1];
        #pragma unroll
        for (int i = 0; i < H1; ++i) { w1r[i] = w1p[i]; b1r[i] = b1p[i]; }
        float w2r[H1 * H2];
        #pragma unroll
        for (int k = 0; k < H1 * H2; ++k) w2r[k] = w2p[k];
        float b2r[H2], w3r[H2];
        #pragma unroll
        for (int j = 0; j < H2; ++j) { b2r[j] = b2p[j]; w3r[j] = w3p[j]; }

        v2f xs;
        xs.x = xt[lane * LDS_STRIDE + s];
        xs.y = xt[(lane + 64) * LDS_STRIDE + s];

        // layer 1: t = tanh(x w1 + b1); p = (1-t^2) w1; q' = t (1-t^2) w1^2
        // (true d2 = -2 q'; the -2 is reassociated into the g2 epilogue)
        v2f t[H1], p[H1], q[H1];
        #pragma unroll
        for (int i = 0; i < H1; ++i) {
            v2f u = fma2(xs, bc(w1r[i]), bc(b1r[i]));
            v2f ti = tanh2(u);
            v2f e = fma2(-ti, ti, bc(1.0f));
            t[i] = ti;
            p[i] = e * bc(w1r[i]);
            q[i] = (ti * p[i]) * bc(w1r[i]);
        }

        v2f o = bc(b3), g2a = bc(0.0f);
        #pragma unroll
        for (int j = 0; j < H2; ++j) {
            v2f vv = bc(b2r[j]), a = bc(0.0f), c = bc(0.0f);
            #pragma unroll
            for (int i = 0; i < H1; ++i) {
                v2f wb = bc(w2r[i * H2 + j]);
                vv = fma2(wb, t[i], vv);
                a  = fma2(wb, p[i], a);
                c  = fma2(wb, q[i], c);
            }
            v2f sj = tanh2(vv);
            v2f dj = fma2(-sj, sj, bc(1.0f));            // 1 - s^2
            v2f aa = a * a;
            v2f h  = fma2(sj, aa, c);                    // c' + s a^2
            v2f k  = dj * h;                             // g2_j = -2 k
            o   = fma2(bc(w3r[j]), sj, o);
            g2a = fma2(bc(w3r[j]), k, g2a);              // g2_true = -2 g2a
        }

        // raw outputs overwrite the just-consumed xt column (same wave, same iter)
        xt[lane * LDS_STRIDE + s] = o.x;
        xt[(lane + 64) * LDS_STRIDE + s] = o.y;

        // per-pair partial sums, horizontal add, wave butterfly reduce
        v2f s2v = o * o;
        v2f s3v = (g2a * g2a) * bc(4.0f);                // (-2 g2a)^2
        float s1 = o.x + o.y;
        float s2 = s2v.x + s2v.y;
        float s3 = s3v.x + s3v.y;
        #pragma unroll
        for (int off = 32; off > 0; off >>= 1) {
            s1 += __shfl_xor(s1, off);
            s2 += __shfl_xor(s2, off);
            s3 += __shfl_xor(s3, off);
        }
        if (lane == 0) {
            partial[(size_t)(0 * SN + s) * GRID + blk] = s1;
            partial[(size_t)(1 * SN + s) * GRID + blk] = s2;
            partial[(size_t)(2 * SN + s) * GRID + blk] = s3;
        }
    }
    __syncthreads();

    // coalesced raw-output store: lane reads 4 floats (2-way max, free)
    float4* po = (float4*)out;
    const size_t base = (size_t)blk * (ROWS * SN / 4);
    #pragma unroll
    for (int it = 0; it < 2; ++it) {
        int v = it * TPB + tid;
        int r = v >> 3;
        int c = (v & 7) << 2;
        const float* src = &xt[r * LDS_STRIDE + c];
        float4 w; w.x = src[0]; w.y = src[1]; w.z = src[2]; w.w = src[3];
        po[base + v] = w;
    }
}

// 96 blocks: block b sums partial[b][0..GRID) (coalesced) -> acc[b] (double)
__global__ __launch_bounds__(256) void k_reduce(const float* __restrict__ partial,
                                                double* __restrict__ acc)
{
    const float* p = partial + (size_t)blockIdx.x * GRID;
    double s = 0.0;
    for (int i = threadIdx.x; i < GRID; i += 256) s += (double)p[i];
    #pragma unroll
    for (int off = 32; off > 0; off >>= 1) s += __shfl_down(s, off);
    __shared__ double ws[4];
    if ((threadIdx.x & 63) == 0) ws[threadIdx.x >> 6] = s;
    __syncthreads();
    if (threadIdx.x == 0) acc[blockIdx.x] = ws[0] + ws[1] + ws[2] + ws[3];
}

// stats recomputed per block from acc (96 doubles, cheap); block 0 writes loss
__global__ __launch_bounds__(256) void k_norm(float* __restrict__ out,
                                              const double* __restrict__ acc)
{
    __shared__ float mean_s[SN], inv_s[SN];
    const int tid = threadIdx.x;
    if (tid < SN) {
        const double invB = 1.0 / (double)BATCH;
        double mean = acc[tid] * invB;
        double var = acc[SN + tid] * invB - mean * mean;
        if (var < 0.0) var = 0.0;
        mean_s[tid] = (float)mean;
        inv_s[tid] = (float)(1.0 / sqrt(var + 1e-10));
    }
    if (blockIdx.x == 0 && tid == 0) {
        const double invB = 1.0 / (double)BATCH;
        double sum = 0.0;
        for (int s = 0; s < SN; ++s) {
            double mean = acc[s] * invB;
            double var = acc[SN + s] * invB - mean * mean;
            if (var < 0.0) var = 0.0;
            sum += (acc[2 * SN + s] * invB) / sqrt(var);   // no eps (matches ref)
        }
        out[(size_t)BATCH * SN] = (float)(0.001 * sum);
    }
    __syncthreads();
    const int v = blockIdx.x * 256 + tid;                  // float4 index
    float4* p = (float4*)out;
    float4 val = p[v];
    const int c = (v & 7) << 2;                            // subnet base
    val.x = (val.x - mean_s[c + 0]) * inv_s[c + 0];
    val.y = (val.y - mean_s[c + 1]) * inv_s[c + 1];
    val.z = (val.z - mean_s[c + 2]) * inv_s[c + 2];
    val.w = (val.w - mean_s[c + 3]) * inv_s[c + 3];
    p[v] = val;
}

extern "C" void kernel_launch(void* const* d_in, const int* in_sizes, int n_in,
                              void* d_out, int out_size, void* d_ws, size_t ws_size,
                              hipStream_t stream) {
    const float* x  = (const float*)d_in[0];
    const float* W1 = (const float*)d_in[1];
    const float* B1 = (const float*)d_in[2];
    const float* W2 = (const float*)d_in[3];
    const float* B2 = (const float*)d_in[4];
    const float* W3 = (const float*)d_in[5];
    const float* B3 = (const float*)d_in[6];

    float* out = (float*)d_out;                 // [BATCH*SN] out_bn, then [1] loss
    float* partial = (float*)d_ws;              // [3*SN][GRID] f32, fully overwritten
    double* acc = (double*)((char*)d_ws + (size_t)3 * SN * GRID * sizeof(float));

    k_main<<<GRID, TPB, 0, stream>>>(x, W1, B1, W2, B2, W3, B3, out, partial);
    k_reduce<<<3 * SN, 256, 0, stream>>>(partial, acc);
    k_norm<<<(BATCH * SN / 4) / 256, 256, 0, stream>>>(out, acc);
}

// Round 10
// 119.786 us; speedup vs baseline: 2.3293x; 1.0081x over previous
//
#include <hip/hip_runtime.h>

#define BATCH 131072
#define SN 32
#define H1 10
#define H2 6
#define ROWS 128                           // rows per block; lane pairs (lane, lane+64)
#define GRID (BATCH / ROWS)                // 1024
#define TPB 512                            // 8 waves/block -> 32 waves/CU at 4 blocks/CU
#define LDS_STRIDE 33                      // bank = (row + s) % 32 -> 2-way (free)

typedef float v2f __attribute__((ext_vector_type(2)));

__device__ __forceinline__ v2f bc(float s) { v2f r; r.x = s; r.y = s; return r; }
__device__ __forceinline__ v2f fma2(v2f a, v2f b, v2f c) {
    return __builtin_elementwise_fma(a, b, c);   // -> v_pk_fma_f32
}
__device__ __forceinline__ v2f tanh2(v2f x) {
    // tanh(x) = 1 - 2/(exp(2x)+1); exp/rcp scalar per component, rest packed
    v2f x2 = x + x;
    v2f e; e.x = __expf(x2.x); e.y = __expf(x2.y);
    v2f e1 = e + bc(1.0f);
    v2f r; r.x = __builtin_amdgcn_rcpf(e1.x); r.y = __builtin_amdgcn_rcpf(e1.y);
    return fma2(bc(-2.0f), r, bc(1.0f));
}

// DPP wave64 sum (LLVM AtomicOptimizer reduction): row_shr 1/2/4/8 +
// row_bcast:15 (rows 1,3) + row_bcast:31 (rows 2,3); total in lane 63.
// VALU-pipe only -- replaces 5 dependent ds_bpermute levels (~350 cyc serial
// LDS-pipe latency per iter) that R9 couldn't hide.
__device__ __forceinline__ float wave_sum(float v) {
    v += __int_as_float(__builtin_amdgcn_update_dpp(
            0, __float_as_int(v), 0x111, 0xf, 0xf, false));   // row_shr:1
    v += __int_as_float(__builtin_amdgcn_update_dpp(
            0, __float_as_int(v), 0x112, 0xf, 0xf, false));   // row_shr:2
    v += __int_as_float(__builtin_amdgcn_update_dpp(
            0, __float_as_int(v), 0x114, 0xf, 0xf, false));   // row_shr:4
    v += __int_as_float(__builtin_amdgcn_update_dpp(
            0, __float_as_int(v), 0x118, 0xf, 0xf, false));   // row_shr:8
    v += __int_as_float(__builtin_amdgcn_update_dpp(
            0, __float_as_int(v), 0x142, 0xa, 0xf, false));   // row_bcast:15
    v += __int_as_float(__builtin_amdgcn_update_dpp(
            0, __float_as_int(v), 0x143, 0xc, 0xf, false));   // row_bcast:31
    return v;                                                  // lane 63 holds sum
}

// 1024 blocks x 512 threads (8 waves); block: 128 rows x 32 subnets; wave w
// handles subnets s = si*8+w (si<4), each lane computes a ROW PAIR via packed
// fp32. Column s of xt is last read by its owning wave in the same iteration,
// so raw outputs overwrite xt in place (16.9 KB LDS).
// Resource math: VGPR~48<=64 (8 waves/SIMD), LDS 16.9*4=68KB, 2048 thr/CU
// -> exactly 4 blocks/CU -> 32 waves/CU. NO min-waves hint (R7 spill lesson).
__global__ __launch_bounds__(TPB) void k_main(
    const float* __restrict__ x,
    const float* __restrict__ W1, const float* __restrict__ B1,
    const float* __restrict__ W2, const float* __restrict__ B2,
    const float* __restrict__ W3, const float* __restrict__ B3,
    float* __restrict__ out, float* __restrict__ partial /* [3*SN][GRID] */)
{
    __shared__ float xt[ROWS * LDS_STRIDE];   // 16.9 KB (x tile, then raw outputs)
    const int tid = threadIdx.x;
    const int lane = tid & 63;
    const int wave = tid >> 6;                // 0..7
    const int blk = blockIdx.x;

    // stage 128x32 x-tile coalesced, transpose-pad into LDS (2 float4/thread)
    const float4* xv = (const float4*)(x + (size_t)blk * ROWS * SN);
    #pragma unroll
    for (int it = 0; it < 2; ++it) {
        int v = it * TPB + tid;
        float4 val = xv[v];
        int r = v >> 3;                       // 8 float4 per row
        int c = (v & 7) << 2;
        float* dst = &xt[r * LDS_STRIDE + c];
        dst[0] = val.x; dst[1] = val.y; dst[2] = val.z; dst[3] = val.w;
    }
    __syncthreads();

    #pragma unroll 1
    for (int si = 0; si < 4; ++si) {
        // wave-uniform subnet id -> params land in SGPRs via s_load
        const int s = __builtin_amdgcn_readfirstlane(si * 8 + wave);
        const float* w1p = W1 + s * H1;
        const float* b1p = B1 + s * H1;
        const float* w2p = W2 + s * H1 * H2;
        const float* b2p = B2 + s * H2;
        const float* w3p = W3 + s * H2;
        const float b3 = B3[s];

        float w1r[H1], b1r[H1];
        #pragma unroll
        for (int i = 0; i < H1; ++i) { w1r[i] = w1p[i]; b1r[i] = b1p[i]; }
        float w2r[H1 * H2];
        #pragma unroll
        for (int k = 0; k < H1 * H2; ++k) w2r[k] = w2p[k];
        float b2r[H2], w3r[H2];
        #pragma unroll
        for (int j = 0; j < H2; ++j) { b2r[j] = b2p[j]; w3r[j] = w3p[j]; }

        v2f xs;
        xs.x = xt[lane * LDS_STRIDE + s];
        xs.y = xt[(lane + 64) * LDS_STRIDE + s];

        // layer 1: t = tanh(x w1 + b1); p = (1-t^2) w1; q' = t (1-t^2) w1^2
        // (true d2 = -2 q'; the -2 is reassociated into the g2 epilogue)
        v2f t[H1], p[H1], q[H1];
        #pragma unroll
        for (int i = 0; i < H1; ++i) {
            v2f u = fma2(xs, bc(w1r[i]), bc(b1r[i]));
            v2f ti = tanh2(u);
            v2f e = fma2(-ti, ti, bc(1.0f));
            t[i] = ti;
            p[i] = e * bc(w1r[i]);
            q[i] = (ti * p[i]) * bc(w1r[i]);
        }

        v2f o = bc(b3), g2a = bc(0.0f);
        #pragma unroll
        for (int j = 0; j < H2; ++j) {
            v2f vv = bc(b2r[j]), a = bc(0.0f), c = bc(0.0f);
            #pragma unroll
            for (int i = 0; i < H1; ++i) {
                v2f wb = bc(w2r[i * H2 + j]);
                vv = fma2(wb, t[i], vv);
                a  = fma2(wb, p[i], a);
                c  = fma2(wb, q[i], c);
            }
            v2f sj = tanh2(vv);
            v2f dj = fma2(-sj, sj, bc(1.0f));            // 1 - s^2
            v2f aa = a * a;
            v2f h  = fma2(sj, aa, c);                    // c' + s a^2
            v2f k  = dj * h;                             // g2_j = -2 k
            o   = fma2(bc(w3r[j]), sj, o);
            g2a = fma2(bc(w3r[j]), k, g2a);              // g2_true = -2 g2a
        }

        // raw outputs overwrite the just-consumed xt column (same wave, same iter)
        xt[lane * LDS_STRIDE + s] = o.x;
        xt[(lane + 64) * LDS_STRIDE + s] = o.y;

        // per-pair sums -> DPP wave reduce (VALU pipe; result in lane 63)
        v2f s2v = o * o;
        v2f s3v = (g2a * g2a) * bc(4.0f);                // (-2 g2a)^2
        float s1 = wave_sum(o.x + o.y);
        float s2 = wave_sum(s2v.x + s2v.y);
        float s3 = wave_sum(s3v.x + s3v.y);
        if (lane == 63) {
            partial[(size_t)(0 * SN + s) * GRID + blk] = s1;
            partial[(size_t)(1 * SN + s) * GRID + blk] = s2;
            partial[(size_t)(2 * SN + s) * GRID + blk] = s3;
        }
    }
    __syncthreads();

    // coalesced raw-output store: lane reads 4 floats (2-way max, free)
    float4* po = (float4*)out;
    const size_t base = (size_t)blk * (ROWS * SN / 4);
    #pragma unroll
    for (int it = 0; it < 2; ++it) {
        int v = it * TPB + tid;
        int r = v >> 3;
        int c = (v & 7) << 2;
        const float* src = &xt[r * LDS_STRIDE + c];
        float4 w; w.x = src[0]; w.y = src[1]; w.z = src[2]; w.w = src[3];
        po[base + v] = w;
    }
}

// 96 blocks: block b sums partial[b][0..GRID) (coalesced) -> acc[b] (double)
__global__ __launch_bounds__(256) void k_reduce(const float* __restrict__ partial,
                                                double* __restrict__ acc)
{
    const float* p = partial + (size_t)blockIdx.x * GRID;
    double s = 0.0;
    for (int i = threadIdx.x; i < GRID; i += 256) s += (double)p[i];
    #pragma unroll
    for (int off = 32; off > 0; off >>= 1) s += __shfl_down(s, off);
    __shared__ double ws[4];
    if ((threadIdx.x & 63) == 0) ws[threadIdx.x >> 6] = s;
    __syncthreads();
    if (threadIdx.x == 0) acc[blockIdx.x] = ws[0] + ws[1] + ws[2] + ws[3];
}

// stats recomputed per block from acc (96 doubles, cheap); block 0 writes loss
__global__ __launch_bounds__(256) void k_norm(float* __restrict__ out,
                                              const double* __restrict__ acc)
{
    __shared__ float mean_s[SN], inv_s[SN];
    const int tid = threadIdx.x;
    if (tid < SN) {
        const double invB = 1.0 / (double)BATCH;
        double mean = acc[tid] * invB;
        double var = acc[SN + tid] * invB - mean * mean;
        if (var < 0.0) var = 0.0;
        mean_s[tid] = (float)mean;
        inv_s[tid] = (float)(1.0 / sqrt(var + 1e-10));
    }
    if (blockIdx.x == 0 && tid == 0) {
        const double invB = 1.0 / (double)BATCH;
        double sum = 0.0;
        for (int s = 0; s < SN; ++s) {
            double mean = acc[s] * invB;
            double var = acc[SN + s] * invB - mean * mean;
            if (var < 0.0) var = 0.0;
            sum += (acc[2 * SN + s] * invB) / sqrt(var);   // no eps (matches ref)
        }
        out[(size_t)BATCH * SN] = (float)(0.001 * sum);
    }
    __syncthreads();
    const int v = blockIdx.x * 256 + tid;                  // float4 index
    float4* p = (float4*)out;
    float4 val = p[v];
    const int c = (v & 7) << 2;                            // subnet base
    val.x = (val.x - mean_s[c + 0]) * inv_s[c + 0];
    val.y = (val.y - mean_s[c + 1]) * inv_s[c + 1];
    val.z = (val.z - mean_s[c + 2]) * inv_s[c + 2];
    val.w = (val.w - mean_s[c + 3]) * inv_s[c + 3];
    p[v] = val;
}

extern "C" void kernel_launch(void* const* d_in, const int* in_sizes, int n_in,
                              void* d_out, int out_size, void* d_ws, size_t ws_size,
                              hipStream_t stream) {
    const float* x  = (const float*)d_in[0];
    const float* W1 = (const float*)d_in[1];
    const float* B1 = (const float*)d_in[2];
    const float* W2 = (const float*)d_in[3];
    const float* B2 = (const float*)d_in[4];
    const float* W3 = (const float*)d_in[5];
    const float* B3 = (const float*)d_in[6];

    float* out = (float*)d_out;                 // [BATCH*SN] out_bn, then [1] loss
    float* partial = (float*)d_ws;              // [3*SN][GRID] f32, fully overwritten
    double* acc = (double*)((char*)d_ws + (size_t)3 * SN * GRID * sizeof(float));

    k_main<<<GRID, TPB, 0, stream>>>(x, W1, B1, W2, B2, W3, B3, out, partial);
    k_reduce<<<3 * SN, 256, 0, stream>>>(partial, acc);
    k_norm<<<(BATCH * SN / 4) / 256, 256, 0, stream>>>(out, acc);
}